// Round 3
// baseline (5322.325 us; speedup 1.0000x reference)
//
#include <hip/hip_runtime.h>
#include <math.h>

#define EE 819200          // edges total
#define BGRAPH 8192        // graphs
constexpr int TPB = 512;   // threads per block, fused GCN kernel
constexpr int NW  = TPB / 64;   // 8 waves
// LDS row stride: multiple of 4 (16B-aligned float4 rows), ==4 mod 32 so
// lane-per-row float4 reads spread across all 32 banks conflict-free.
constexpr int LDX = 164;

// ---------------------------------------------------------------------------
// Fused per-graph 3-layer GCN + global max pool, aggregate-first form:
//   GCNConv(X) = (ÂX)W + b
// GEMM is wave-scalar-broadcast: lanes = nodes (row per lane), each wave owns
// a feature slice so W reads are wave-uniform -> scalar s_load (K$ path, no
// VALU slots, no vector-L1 traffic). Max pool = shfl_xor butterfly per wave.
// ---------------------------------------------------------------------------

template<int FIN>
__device__ inline void agg_block(const float* __restrict__ in,
                                 float* __restrict__ out,
                                 const int*   __restrict__ insrc,
                                 const float* __restrict__ insn,
                                 const int*   __restrict__ inoff,
                                 const float* __restrict__ selfw)
{
    for (int idx = threadIdx.x; idx < 50 * FIN; idx += TPB) {
        const int n = idx / FIN;
        const int f = idx - n * FIN;
        float acc = selfw[n] * in[n * LDX + f];
        const int j1 = inoff[n + 1];
        for (int j = inoff[n]; j < j1; ++j)
            acc += insn[j] * in[insrc[j] * LDX + f];
        out[n * LDX + f] = acc;
    }
}

// Y = relu(Xa @ W + b). Lane l handles node l (rows 50..63 clamped to zeroed
// row 51); wave wid handles features [f0, f0+nf). W/bias reads are uniform ->
// scalar loads. Benign overread of W past column FOUT (wraps into next row;
// last row overreads <=16B into page slack) -- those acc[j] are never stored.
template<int FIN, int FOUT, bool POOL>
__device__ inline void gemm_wave(const float* __restrict__ Xa,
                                 const float* __restrict__ W,
                                 const float* __restrict__ bias,
                                 float* __restrict__ Yout,   // LDS [52][LDX] or gmax[312]
                                 int wid, int lane)
{
    constexpr int NF = (FOUT + NW - 1) / NW;
    const int f0 = wid * NF;                       // wave-uniform
    const int nf = (FOUT - f0) < NF ? (FOUT - f0) : NF;
    const int nrow = lane < 52 ? lane : 51;
    float acc[NF];
#pragma unroll
    for (int j = 0; j < NF; ++j) acc[j] = 0.0f;

    const float* Xr = Xa + nrow * LDX;
    constexpr int K4 = FIN & ~3;
    for (int k0 = 0; k0 < K4; k0 += 4) {
        const float4 av = *reinterpret_cast<const float4*>(Xr + k0);
        const float* Wk = W + (size_t)k0 * FOUT + f0;
#pragma unroll
        for (int kk = 0; kk < 4; ++kk) {
            const float a = kk == 0 ? av.x : kk == 1 ? av.y : kk == 2 ? av.z : av.w;
#pragma unroll
            for (int j = 0; j < NF; ++j)
                acc[j] = fmaf(a, Wk[kk * FOUT + j], acc[j]);
        }
    }
#pragma unroll
    for (int k = K4; k < FIN; ++k) {               // tail (<=3 iters)
        const float a = Xr[k];
        const float* Wk = W + (size_t)k * FOUT + f0;
#pragma unroll
        for (int j = 0; j < NF; ++j)
            acc[j] = fmaf(a, Wk[j], acc[j]);
    }

    if constexpr (POOL) {
#pragma unroll
        for (int j = 0; j < NF; ++j) {
            if (j < nf) {                          // uniform guard
                float m = (lane < 50) ? fmaxf(acc[j] + bias[f0 + j], 0.0f) : 0.0f;
#pragma unroll
                for (int s = 32; s > 0; s >>= 1)
                    m = fmaxf(m, __shfl_xor(m, s, 64));
                if (lane == 0) Yout[f0 + j] = m;   // features wave-disjoint
            }
        }
    } else {
        if (lane < 50) {
#pragma unroll
            for (int j = 0; j < NF; ++j)
                if (j < nf)
                    Yout[lane * LDX + f0 + j] = fmaxf(acc[j] + bias[f0 + j], 0.0f);
        }
    }
}

__global__ __launch_bounds__(TPB, 2) void gcn_fused(
    const float* __restrict__ X,        // [N,78]
    const int*   __restrict__ srcA,     // [E]
    const int*   __restrict__ dstA,     // [E]
    const float* __restrict__ Wc1, const float* __restrict__ bc1,
    const float* __restrict__ Wc2, const float* __restrict__ bc2,
    const float* __restrict__ Wc3, const float* __restrict__ bc3,
    float* __restrict__ G)              // [B,312]
{
    __shared__ float bufA[52 * LDX];
    __shared__ float bufB[52 * LDX];
    __shared__ int   es[100], ed[100];
    __shared__ int   insrc[100];
    __shared__ float insn[100];
    __shared__ int   inoff[51];
    __shared__ int   cnt[50];
    __shared__ float dinvs[50];
    __shared__ float selfw[50];
    __shared__ float gmaxf[312];

    const int b    = blockIdx.x;
    const int nb   = b * 50;
    const int eb   = b * 100;
    const int tid  = threadIdx.x;
    const int lane = tid & 63;
    const int wid  = __builtin_amdgcn_readfirstlane(tid >> 6);

    for (int i = tid; i < 50; i += TPB) cnt[i] = 0;
    for (int e = tid; e < 100; e += TPB) {
        es[e] = srcA[eb + e] - nb;
        ed[e] = dstA[eb + e] - nb;
    }
    for (int i = tid; i < 2 * LDX; i += TPB) {   // keep pad rows 50,51 zero
        bufA[50 * LDX + i] = 0.0f;
        bufB[50 * LDX + i] = 0.0f;
    }
    __syncthreads();
    for (int e = tid; e < 100; e += TPB) atomicAdd(&cnt[ed[e]], 1);
    __syncthreads();
    for (int n = tid; n < 50; n += TPB) {
        const float dv = 1.0f / sqrtf((float)cnt[n] + 1.0f);
        dinvs[n] = dv;
        selfw[n] = dv * dv;
    }
    __syncthreads();
    if (tid == 0) {                      // tiny serial prefix sum (50 entries)
        int off = 0;
        for (int n = 0; n < 50; ++n) { inoff[n] = off; off += cnt[n]; }
        inoff[50] = off;
    }
    __syncthreads();
    for (int n = tid; n < 50; n += TPB) cnt[n] = 0;
    __syncthreads();
    for (int e = tid; e < 100; e += TPB) {   // counting-sort edges by dst
        const int d = ed[e];
        const int p = inoff[d] + atomicAdd(&cnt[d], 1);
        insrc[p] = es[e];
        insn[p]  = dinvs[es[e]] * dinvs[d];
    }
    // load X tile [50,78] -> bufA
    for (int idx = tid; idx < 50 * 78; idx += TPB) {
        const int n = idx / 78, c = idx - n * 78;
        bufA[n * LDX + c] = X[(size_t)(nb + n) * 78 + c];
    }
    __syncthreads();

    // layer 1: agg(78) then 78->78 GEMM
    agg_block<78>(bufA, bufB, insrc, insn, inoff, selfw);
    __syncthreads();
    gemm_wave<78, 78, false>(bufB, Wc1, bc1, bufA, wid, lane);
    __syncthreads();

    // layer 2: agg(78) then 78->156 GEMM
    agg_block<78>(bufA, bufB, insrc, insn, inoff, selfw);
    __syncthreads();
    gemm_wave<78, 156, false>(bufB, Wc2, bc2, bufA, wid, lane);
    __syncthreads();

    // layer 3: agg(156) then 156->312 GEMM + fused bias/relu/maxpool
    agg_block<156>(bufA, bufB, insrc, insn, inoff, selfw);
    __syncthreads();
    gemm_wave<156, 312, true>(bufB, Wc3, bc3, gmaxf, wid, lane);
    __syncthreads();
    for (int f = tid; f < 312; f += TPB)
        G[(size_t)b * 312 + f] = gmaxf[f];
}

// ---------------------------------------------------------------------------
// Generic fp32 tiled GEMM: C[m, coff+n] = act(A[M,K] @ W[K,N] + bias[N])
// BM=BN=64, BK=16, 256 threads, 4x4 micro-tile. ldc/coff support writing into
// a strided concat buffer.
// ---------------------------------------------------------------------------
template<bool RELU>
__global__ __launch_bounds__(256) void gemm_f32(
    const float* __restrict__ A, const float* __restrict__ W,
    const float* __restrict__ bias, float* __restrict__ C,
    int M, int N, int K, int ldc, int coff)
{
    __shared__ float As[64][17];   // padded: conflict-free k-reads
    __shared__ float Ws[16][64];
    const int bm = blockIdx.x * 64;
    const int bn = blockIdx.y * 64;
    const int tid = threadIdx.x;
    const int tx = tid & 15;       // n dim
    const int ty = tid >> 4;       // m dim
    float acc[4][4] = {};

    for (int k0 = 0; k0 < K; k0 += 16) {
        for (int i = tid; i < 64 * 16; i += 256) {
            const int m = i >> 4, kk = i & 15;
            const int gm = bm + m, gk = k0 + kk;
            As[m][kk] = (gm < M && gk < K) ? A[(size_t)gm * K + gk] : 0.0f;
        }
        for (int i = tid; i < 16 * 64; i += 256) {
            const int kk = i >> 6, n = i & 63;
            const int gk = k0 + kk, gn = bn + n;
            Ws[kk][n] = (gk < K && gn < N) ? W[(size_t)gk * N + gn] : 0.0f;
        }
        __syncthreads();
#pragma unroll
        for (int kk = 0; kk < 16; ++kk) {
            const float4 wv = *reinterpret_cast<const float4*>(&Ws[kk][tx * 4]);
            float a[4];
#pragma unroll
            for (int i = 0; i < 4; ++i) a[i] = As[ty * 4 + i][kk];
#pragma unroll
            for (int i = 0; i < 4; ++i) {
                acc[i][0] += a[i] * wv.x;
                acc[i][1] += a[i] * wv.y;
                acc[i][2] += a[i] * wv.z;
                acc[i][3] += a[i] * wv.w;
            }
        }
        __syncthreads();
    }
#pragma unroll
    for (int i = 0; i < 4; ++i) {
        const int gm = bm + ty * 4 + i;
        if (gm >= M) continue;
#pragma unroll
        for (int j = 0; j < 4; ++j) {
            const int gn = bn + tx * 4 + j;
            if (gn >= N) continue;
            float v = acc[i][j] + bias[gn];
            if (RELU) v = fmaxf(v, 0.0f);
            C[(size_t)gm * ldc + coff + gn] = v;
        }
    }
}

// ---------------------------------------------------------------------------
// Row-wise L2 normalize: Y[r,:] = X[r,:] / max(||X[r,:]||_2, 1e-12), 954 cols
// ---------------------------------------------------------------------------
__global__ __launch_bounds__(256) void l2norm_rows(
    const float* __restrict__ X, float* __restrict__ Y)
{
    const int r = blockIdx.x;
    const float* row = X + (size_t)r * 954;
    float ss = 0.0f;
    for (int c = threadIdx.x; c < 954; c += 256) { const float v = row[c]; ss += v * v; }
    for (int off = 32; off > 0; off >>= 1) ss += __shfl_down(ss, off, 64);
    __shared__ float part[4];
    if ((threadIdx.x & 63) == 0) part[threadIdx.x >> 6] = ss;
    __syncthreads();
    if (threadIdx.x == 0) {
        const float s = part[0] + part[1] + part[2] + part[3];
        part[0] = 1.0f / fmaxf(sqrtf(s), 1e-12f);
    }
    __syncthreads();
    const float sc = part[0];
    for (int c = threadIdx.x; c < 954; c += 256)
        Y[(size_t)r * 954 + c] = row[c] * sc;
}

// ---------------------------------------------------------------------------

extern "C" void kernel_launch(void* const* d_in, const int* in_sizes, int n_in,
                              void* d_out, int out_size, void* d_ws, size_t ws_size,
                              hipStream_t stream)
{
    (void)in_sizes; (void)n_in; (void)out_size; (void)ws_size;
    const float* x1   = (const float*)d_in[0];
    const int*   ei1  = (const int*)d_in[1];
    const float* x2   = (const float*)d_in[3];
    const int*   ei2  = (const int*)d_in[4];
    const float* cell = (const float*)d_in[6];
    const float* Wc1 = (const float*)d_in[7],  *bc1 = (const float*)d_in[8];
    const float* Wc2 = (const float*)d_in[9],  *bc2 = (const float*)d_in[10];
    const float* Wc3 = (const float*)d_in[11], *bc3 = (const float*)d_in[12];
    const float* Wg1 = (const float*)d_in[13], *bg1 = (const float*)d_in[14];
    const float* Wg2 = (const float*)d_in[15], *bg2 = (const float*)d_in[16];
    const float* Wr1 = (const float*)d_in[17], *br1 = (const float*)d_in[18];
    const float* Wr2 = (const float*)d_in[19], *br2 = (const float*)d_in[20];
    const float* Wr3 = (const float*)d_in[21], *br3 = (const float*)d_in[22];
    const float* Wf1 = (const float*)d_in[23], *bf1 = (const float*)d_in[24];
    const float* Wf2 = (const float*)d_in[25], *bf2 = (const float*)d_in[26];
    const float* Wo  = (const float*)d_in[27], *bo  = (const float*)d_in[28];
    float* out = (float*)d_out;
    float* ws  = (float*)d_ws;

    // workspace layout (floats)
    size_t o = 0;
    float* G1  = ws + o; o += (size_t)BGRAPH * 312;
    float* G2  = ws + o; o += (size_t)BGRAPH * 312;
    float* T   = ws + o; o += (size_t)BGRAPH * 156;
    float* CVN = ws + o; o += (size_t)BGRAPH * 954;
    float* C1  = ws + o; o += (size_t)BGRAPH * 512;
    float* C2  = ws + o; o += (size_t)BGRAPH * 256;
    float* XC  = ws + o; o += (size_t)BGRAPH * 384;
    float* Hh1 = ws + o; o += (size_t)BGRAPH * 256;
    float* Hh2 = ws + o; o += (size_t)BGRAPH * 128;

    // drug branches (GCN x3 + maxpool), fused per graph
    gcn_fused<<<BGRAPH, TPB, 0, stream>>>(x1, ei1, ei1 + EE, Wc1, bc1, Wc2, bc2, Wc3, bc3, G1);
    gcn_fused<<<BGRAPH, TPB, 0, stream>>>(x2, ei2, ei2 + EE, Wc1, bc1, Wc2, bc2, Wc3, bc3, G2);

    // cell row normalize
    l2norm_rows<<<BGRAPH, 256, 0, stream>>>(cell, CVN);

    dim3 blk(256);
    auto gg = [](int M, int N) { return dim3((unsigned)((M + 63) / 64), (unsigned)((N + 63) / 64)); };

    // drug heads -> XC[:,0:128] and XC[:,128:256]
    gemm_f32<true ><<<gg(8192, 156), blk, 0, stream>>>(G1, Wg1, bg1, T,  8192, 156, 312, 156, 0);
    gemm_f32<false><<<gg(8192, 128), blk, 0, stream>>>(T,  Wg2, bg2, XC, 8192, 128, 156, 384, 0);
    gemm_f32<true ><<<gg(8192, 156), blk, 0, stream>>>(G2, Wg1, bg1, T,  8192, 156, 312, 156, 0);
    gemm_f32<false><<<gg(8192, 128), blk, 0, stream>>>(T,  Wg2, bg2, XC, 8192, 128, 156, 384, 128);

    // cell MLP -> XC[:,256:384]
    gemm_f32<true ><<<gg(8192, 512), blk, 0, stream>>>(CVN, Wr1, br1, C1, 8192, 512, 954, 512, 0);
    gemm_f32<true ><<<gg(8192, 256), blk, 0, stream>>>(C1,  Wr2, br2, C2, 8192, 256, 512, 256, 0);
    gemm_f32<false><<<gg(8192, 128), blk, 0, stream>>>(C2,  Wr3, br3, XC, 8192, 128, 256, 384, 256);

    // head
    gemm_f32<true ><<<gg(8192, 256), blk, 0, stream>>>(XC,  Wf1, bf1, Hh1, 8192, 256, 384, 256, 0);
    gemm_f32<true ><<<gg(8192, 128), blk, 0, stream>>>(Hh1, Wf2, bf2, Hh2, 8192, 128, 256, 128, 0);
    gemm_f32<false><<<gg(8192, 2),   blk, 0, stream>>>(Hh2, Wo,  bo,  out, 8192, 2,   128, 2,   0);
}

// Round 4
// 1358.854 us; speedup vs baseline: 3.9168x; 3.9168x over previous
//
#include <hip/hip_runtime.h>
#include <math.h>

#define EE 819200          // edges total
#define BGRAPH 8192        // graphs
constexpr int GT = 512;    // threads, graph kernel (8 waves)

typedef __attribute__((ext_vector_type(8))) short bf16x8;   // 4 VGPRs = 8 bf16
typedef __attribute__((ext_vector_type(4))) float f32x4;

// ---- fp32 -> bf16 split (RNE), a ~= hi + lo, |a-(hi+lo)| <= 2^-18 |a| ----
__device__ inline unsigned short f2bf(float x) {
    unsigned u = __float_as_uint(x);
    u += 0x7fffu + ((u >> 16) & 1u);
    return (unsigned short)(u >> 16);
}
__device__ inline float bf2f(unsigned short h) {
    return __uint_as_float(((unsigned)h) << 16);
}
__device__ inline void split2(float v, unsigned short& hi, unsigned short& lo) {
    hi = f2bf(v);
    lo = f2bf(v - bf2f(hi));
}

// ---------------------------------------------------------------------------
// Weight prep: W[K][N] fp32 -> fragment-ordered hi/lo bf16, zero-padded to
// (KS*32) x (NT*16). Element order matches the GEMM's B-fragment loads:
//   idx = (((nt*KS + ks)*64 + lane)*8 + r)  <->  k = ks*32+(lane>>4)*8+r,
//   n = nt*16 + (lane&15).
// The SAME (lane>>4, r) -> k map is used for A staging, so any true HW k-order
// cancels (consistent-sigma argument).
// ---------------------------------------------------------------------------
__global__ __launch_bounds__(256) void wprep(
    const float* __restrict__ W, int K, int N, int KS, int NT,
    unsigned short* __restrict__ Bh, unsigned short* __restrict__ Bl)
{
    const int idx = blockIdx.x * 256 + threadIdx.x;
    if (idx >= NT * KS * 512) return;
    const int r    = idx & 7;
    const int lane = (idx >> 3) & 63;
    const int rest = idx >> 9;
    const int ks   = rest % KS;
    const int nt   = rest / KS;
    const int k = ks * 32 + ((lane >> 4) << 3) + r;
    const int n = nt * 16 + (lane & 15);
    const float v = (k < K && n < N) ? W[(size_t)k * N + n] : 0.f;
    unsigned short h, l; split2(v, h, l);
    Bh[idx] = h; Bl[idx] = l;
}

// ---------------------------------------------------------------------------
// Per-graph fused 3-layer GCN + max pool, bf16x3 MFMA.
// 8 waves = 2 m-groups (32 rows) x 4 n-groups. A (aggregated activations) as
// hi/lo bf16 in LDS [64][168] (stride 168 -> balanced LDS banks for b128 frag
// reads). W fragments direct from global (L2-resident).
// ---------------------------------------------------------------------------

template<int KS, int NI>   // K-steps; n-tiles per wave (nt = ng + 4*i)
__device__ inline void layer_run(const unsigned short* __restrict__ Bh,
                                 const unsigned short* __restrict__ Bl,
                                 const unsigned short* Ah, const unsigned short* Al,
                                 f32x4 (&acc)[2][5], int mg, int ng, int lane)
{
#pragma unroll
    for (int m = 0; m < 2; ++m)
#pragma unroll
        for (int i = 0; i < NI; ++i) acc[m][i] = (f32x4){0.f, 0.f, 0.f, 0.f};
    const int g8 = (lane >> 4) << 3;
    for (int ks = 0; ks < KS; ++ks) {
        bf16x8 ah[2], al[2];
#pragma unroll
        for (int m = 0; m < 2; ++m) {
            const int off = (mg * 32 + m * 16 + (lane & 15)) * 168 + ks * 32 + g8;
            ah[m] = *(const bf16x8*)(Ah + off);
            al[m] = *(const bf16x8*)(Al + off);
        }
#pragma unroll
        for (int i = 0; i < NI; ++i) {
            const int nt = ng + (i << 2);
            const size_t bo = (size_t)((nt * KS + ks) * 64 + lane) * 8;
            const bf16x8 bh = *(const bf16x8*)(Bh + bo);
            const bf16x8 bl = *(const bf16x8*)(Bl + bo);
#pragma unroll
            for (int m = 0; m < 2; ++m) {
                acc[m][i] = __builtin_amdgcn_mfma_f32_16x16x32_bf16(ah[m], bh, acc[m][i], 0, 0, 0);
                acc[m][i] = __builtin_amdgcn_mfma_f32_16x16x32_bf16(al[m], bh, acc[m][i], 0, 0, 0);
                acc[m][i] = __builtin_amdgcn_mfma_f32_16x16x32_bf16(ah[m], bl, acc[m][i], 0, 0, 0);
            }
        }
    }
}

// D layout (verified): col = lane&15 (+16*nt), row = (lane>>4)*4 + reg (+16*mt)
template<int NI, int NCOL>
__device__ inline void epi_store(const f32x4 (&acc)[2][5], const float* __restrict__ bias,
                                 float* act, int mg, int ng, int lane)
{
#pragma unroll
    for (int i = 0; i < NI; ++i) {
        const int col = (ng + (i << 2)) * 16 + (lane & 15);
        if (col < NCOL) {
            const float bj = bias[col];
#pragma unroll
            for (int m = 0; m < 2; ++m)
#pragma unroll
                for (int r = 0; r < 4; ++r) {
                    const int row = mg * 32 + m * 16 + ((lane >> 4) << 2) + r;
                    if (row < 50)
                        act[row * 156 + col] = fmaxf(acc[m][i][r] + bj, 0.f);
                }
        }
    }
}

__device__ inline void pool_store(const f32x4 (&acc)[2][5], const float* __restrict__ bias,
                                  unsigned* gmax, int mg, int ng, int lane)
{
#pragma unroll
    for (int i = 0; i < 5; ++i) {
        const int col = (ng + (i << 2)) * 16 + (lane & 15);
        const float bj = (col < 312) ? bias[col] : 0.f;
        float m = 0.f;                      // relu floor == pool identity
#pragma unroll
        for (int mm = 0; mm < 2; ++mm)
#pragma unroll
            for (int r = 0; r < 4; ++r) {
                const int row = mg * 32 + mm * 16 + ((lane >> 4) << 2) + r;
                if (row < 50) m = fmaxf(m, acc[mm][i][r] + bj);
            }
        m = fmaxf(m, __shfl_xor(m, 16, 64));
        m = fmaxf(m, __shfl_xor(m, 32, 64));
        if (lane < 16 && col < 312)
            atomicMax(&gmax[col], __float_as_uint(m));
    }
}

// agg (Â·H) fused with bf16-split -> writes next layer's A fragments
template<int NCOL>
__device__ inline void agg_split(const float* act, unsigned short* Ah, unsigned short* Al,
                                 const int* insrc, const float* insn,
                                 const int* inoff, const float* selfw, int tid)
{
    for (int idx = tid; idx < 50 * NCOL; idx += GT) {
        const int n = idx / NCOL, f = idx - n * NCOL;
        float v = selfw[n] * act[n * 156 + f];
        const int j1 = inoff[n + 1];
        for (int j = inoff[n]; j < j1; ++j)
            v += insn[j] * act[insrc[j] * 156 + f];
        unsigned short h, l; split2(v, h, l);
        Ah[n * 168 + f] = h;
        Al[n * 168 + f] = l;
    }
}

__global__ __launch_bounds__(GT) void gcn_graph(
    const float* __restrict__ X,
    const int* __restrict__ srcA, const int* __restrict__ dstA,
    const unsigned short* __restrict__ W1h, const unsigned short* __restrict__ W1l,
    const unsigned short* __restrict__ W2h, const unsigned short* __restrict__ W2l,
    const unsigned short* __restrict__ W3h, const unsigned short* __restrict__ W3l,
    const float* __restrict__ bc1, const float* __restrict__ bc2, const float* __restrict__ bc3,
    float* __restrict__ G)              // [B,312]
{
    __shared__ unsigned short Ah[64 * 168], Al[64 * 168];   // split A frags
    __shared__ float act[50 * 156];                          // fp32 activations
    __shared__ int   es[100], ed[100], insrc[100];
    __shared__ float insn[100];
    __shared__ int   inoff[51], cnt[50];
    __shared__ float dinvs[50], selfw[50];
    __shared__ unsigned gmax[312];

    const int b = blockIdx.x, nb = b * 50, eb = b * 100, tid = threadIdx.x;
    const int lane = tid & 63;
    const int w = tid >> 6;
    const int mg = w >> 2, ng = w & 3;

    // ---- prologue: zero frag bufs (pad rows/cols stay 0), CSR build, X load
    for (int i = tid; i < 64 * 168; i += GT) { Ah[i] = 0; Al[i] = 0; }
    for (int i = tid; i < 312; i += GT) gmax[i] = 0u;
    for (int i = tid; i < 50; i += GT) cnt[i] = 0;
    for (int e = tid; e < 100; e += GT) { es[e] = srcA[eb + e] - nb; ed[e] = dstA[eb + e] - nb; }
    __syncthreads();
    for (int e = tid; e < 100; e += GT) atomicAdd(&cnt[ed[e]], 1);
    __syncthreads();
    for (int n = tid; n < 50; n += GT) {
        const float dv = 1.0f / sqrtf((float)cnt[n] + 1.0f);
        dinvs[n] = dv; selfw[n] = dv * dv;
    }
    __syncthreads();
    if (tid == 0) { int off = 0; for (int n = 0; n < 50; ++n) { inoff[n] = off; off += cnt[n]; } inoff[50] = off; }
    __syncthreads();
    for (int n = tid; n < 50; n += GT) cnt[n] = 0;
    __syncthreads();
    for (int e = tid; e < 100; e += GT) {          // counting-sort edges by dst
        const int d = ed[e];
        const int p = inoff[d] + atomicAdd(&cnt[d], 1);
        insrc[p] = es[e];
        insn[p]  = dinvs[es[e]] * dinvs[d];
    }
    for (int idx = tid; idx < 50 * 78; idx += GT) {
        const int n = idx / 78, c = idx - n * 78;
        act[n * 156 + c] = X[(size_t)(nb + n) * 78 + c];
    }
    __syncthreads();

    f32x4 acc[2][5];

    // layer 1: agg(X) -> 78x78
    agg_split<78>(act, Ah, Al, insrc, insn, inoff, selfw, tid);
    __syncthreads();
    layer_run<3, 2>(W1h, W1l, Ah, Al, acc, mg, ng, lane);
    epi_store<2, 78>(acc, bc1, act, mg, ng, lane);
    __syncthreads();

    // layer 2: agg -> 78x156
    agg_split<78>(act, Ah, Al, insrc, insn, inoff, selfw, tid);
    __syncthreads();
    layer_run<3, 3>(W2h, W2l, Ah, Al, acc, mg, ng, lane);
    epi_store<3, 156>(acc, bc2, act, mg, ng, lane);
    __syncthreads();

    // layer 3: agg -> 156x312 + fused bias/relu/maxpool
    agg_split<156>(act, Ah, Al, insrc, insn, inoff, selfw, tid);
    __syncthreads();
    layer_run<5, 5>(W3h, W3l, Ah, Al, acc, mg, ng, lane);
    pool_store(acc, bc3, gmax, mg, ng, lane);
    __syncthreads();
    for (int f = tid; f < 312; f += GT)
        G[(size_t)b * 312 + f] = __uint_as_float(gmax[f]);
}

// ---------------------------------------------------------------------------
// Dense bf16x3 MFMA GEMM: C = act(A[M,K] @ W[K,N] + b). BM=64, 4 waves, each
// wave owns 4 m-tiles x NTW n-tiles. A staged+split to LDS per 32-k step.
// ---------------------------------------------------------------------------
template<int NTW, bool RELU>
__global__ __launch_bounds__(256) void gemm_dense(
    const float* __restrict__ A, int lda, int K, int KS,
    const unsigned short* __restrict__ Bh, const unsigned short* __restrict__ Bl,
    const float* __restrict__ bias, int Nout,
    float* __restrict__ C, int ldc, int coff)
{
    __shared__ unsigned short Ahs[64 * 40], Als[64 * 40];
    const int tid = threadIdx.x, lane = tid & 63, w = tid >> 6;
    const int bm = blockIdx.x * 64;
    const int ntb = blockIdx.y * 4 * NTW;
    f32x4 acc[4][NTW];
#pragma unroll
    for (int m = 0; m < 4; ++m)
#pragma unroll
        for (int i = 0; i < NTW; ++i) acc[m][i] = (f32x4){0.f, 0.f, 0.f, 0.f};
    const int g8 = (lane >> 4) << 3;

    for (int ks = 0; ks < KS; ++ks) {
        __syncthreads();
        for (int idx = tid; idx < 2048; idx += 256) {
            const int row = idx >> 5, kk = idx & 31;
            const int k = ks * 32 + kk;
            const float v = (k < K) ? A[(size_t)(bm + row) * lda + k] : 0.f;
            unsigned short h, l; split2(v, h, l);
            Ahs[row * 40 + kk] = h; Als[row * 40 + kk] = l;
        }
        __syncthreads();
        bf16x8 ah[4], al[4];
#pragma unroll
        for (int m = 0; m < 4; ++m) {
            const int off = (m * 16 + (lane & 15)) * 40 + g8;
            ah[m] = *(const bf16x8*)(Ahs + off);
            al[m] = *(const bf16x8*)(Als + off);
        }
#pragma unroll
        for (int i = 0; i < NTW; ++i) {
            const int nt = ntb + w * NTW + i;
            const size_t bo = (size_t)((nt * KS + ks) * 64 + lane) * 8;
            const bf16x8 bh = *(const bf16x8*)(Bh + bo);
            const bf16x8 bl = *(const bf16x8*)(Bl + bo);
#pragma unroll
            for (int m = 0; m < 4; ++m) {
                acc[m][i] = __builtin_amdgcn_mfma_f32_16x16x32_bf16(ah[m], bh, acc[m][i], 0, 0, 0);
                acc[m][i] = __builtin_amdgcn_mfma_f32_16x16x32_bf16(al[m], bh, acc[m][i], 0, 0, 0);
                acc[m][i] = __builtin_amdgcn_mfma_f32_16x16x32_bf16(ah[m], bl, acc[m][i], 0, 0, 0);
            }
        }
    }
#pragma unroll
    for (int i = 0; i < NTW; ++i) {
        const int col = (ntb + w * NTW + i) * 16 + (lane & 15);
        if (col < Nout) {
            const float bj = bias[col];
#pragma unroll
            for (int m = 0; m < 4; ++m)
#pragma unroll
                for (int r = 0; r < 4; ++r) {
                    const int row = bm + m * 16 + ((lane >> 4) << 2) + r;
                    float v = acc[m][i][r] + bj;
                    if (RELU) v = fmaxf(v, 0.f);
                    C[(size_t)row * ldc + coff + col] = v;
                }
        }
    }
}

// ---------------------------------------------------------------------------
// Row-wise L2 normalize: Y[r,:] = X[r,:] / max(||X||, 1e-12), 954 cols
// ---------------------------------------------------------------------------
__global__ __launch_bounds__(256) void l2norm_rows(
    const float* __restrict__ X, float* __restrict__ Y)
{
    const int r = blockIdx.x;
    const float* row = X + (size_t)r * 954;
    float ss = 0.0f;
    for (int c = threadIdx.x; c < 954; c += 256) { const float v = row[c]; ss += v * v; }
    for (int off = 32; off > 0; off >>= 1) ss += __shfl_down(ss, off, 64);
    __shared__ float part[4];
    if ((threadIdx.x & 63) == 0) part[threadIdx.x >> 6] = ss;
    __syncthreads();
    if (threadIdx.x == 0) {
        const float s = part[0] + part[1] + part[2] + part[3];
        part[0] = 1.0f / fmaxf(sqrtf(s), 1e-12f);
    }
    __syncthreads();
    const float sc = part[0];
    for (int c = threadIdx.x; c < 954; c += 256)
        Y[(size_t)r * 954 + c] = row[c] * sc;
}

// final head: out[m,0:2] = Hh2[m,:] @ Wo + bo   (K=128, N=2) — one wave/row
__global__ __launch_bounds__(256) void wo_kernel(
    const float* __restrict__ H, const float* __restrict__ Wo,
    const float* __restrict__ bo, float* __restrict__ out)
{
    const int lane = threadIdx.x & 63;
    const int row = blockIdx.x * 4 + (threadIdx.x >> 6);
    const float a0 = H[(size_t)row * 128 + lane];
    const float a1 = H[(size_t)row * 128 + 64 + lane];
    float s0 = a0 * Wo[lane * 2]     + a1 * Wo[(64 + lane) * 2];
    float s1 = a0 * Wo[lane * 2 + 1] + a1 * Wo[(64 + lane) * 2 + 1];
    for (int off = 32; off > 0; off >>= 1) {
        s0 += __shfl_xor(s0, off, 64);
        s1 += __shfl_xor(s1, off, 64);
    }
    if (lane == 0) { out[row * 2] = s0 + bo[0]; out[row * 2 + 1] = s1 + bo[1]; }
}

// ---------------------------------------------------------------------------

extern "C" void kernel_launch(void* const* d_in, const int* in_sizes, int n_in,
                              void* d_out, int out_size, void* d_ws, size_t ws_size,
                              hipStream_t stream)
{
    (void)in_sizes; (void)n_in; (void)out_size; (void)ws_size;
    const float* x1   = (const float*)d_in[0];
    const int*   ei1  = (const int*)d_in[1];
    const float* x2   = (const float*)d_in[3];
    const int*   ei2  = (const int*)d_in[4];
    const float* cell = (const float*)d_in[6];
    const float* Wc1 = (const float*)d_in[7],  *bc1 = (const float*)d_in[8];
    const float* Wc2 = (const float*)d_in[9],  *bc2 = (const float*)d_in[10];
    const float* Wc3 = (const float*)d_in[11], *bc3 = (const float*)d_in[12];
    const float* Wg1 = (const float*)d_in[13], *bg1 = (const float*)d_in[14];
    const float* Wg2 = (const float*)d_in[15], *bg2 = (const float*)d_in[16];
    const float* Wr1 = (const float*)d_in[17], *br1 = (const float*)d_in[18];
    const float* Wr2 = (const float*)d_in[19], *br2 = (const float*)d_in[20];
    const float* Wr3 = (const float*)d_in[21], *br3 = (const float*)d_in[22];
    const float* Wf1 = (const float*)d_in[23], *bf1 = (const float*)d_in[24];
    const float* Wf2 = (const float*)d_in[25], *bf2 = (const float*)d_in[26];
    const float* Wo  = (const float*)d_in[27], *bo  = (const float*)d_in[28];
    float* out = (float*)d_out;
    float* ws  = (float*)d_ws;

    size_t o = 0;
    auto allocF = [&](size_t n) { float* p = ws + o; o += n; return p; };
    auto allocU = [&](size_t n) { unsigned short* p = (unsigned short*)(ws + o); o += n / 2; return p; };

    float* G1  = allocF((size_t)BGRAPH * 312);
    float* G2  = allocF((size_t)BGRAPH * 312);
    float* T   = allocF((size_t)BGRAPH * 156);
    float* CVN = allocF((size_t)BGRAPH * 954);
    float* C1  = allocF((size_t)BGRAPH * 512);
    float* C2  = allocF((size_t)BGRAPH * 256);
    float* XC  = allocF((size_t)BGRAPH * 384);
    float* H1  = allocF((size_t)BGRAPH * 256);
    float* H2  = allocF((size_t)BGRAPH * 128);

    // swizzled split weights (ushort counts = NT*KS*512)
    const int sWc1 = 8  * 3  * 512, sWc2 = 12 * 3  * 512, sWc3 = 20 * 5  * 512;
    const int sWg1 = 12 * 10 * 512, sWg2 = 8  * 5  * 512;
    const int sWr1 = 32 * 30 * 512, sWr2 = 16 * 16 * 512, sWr3 = 8 * 8 * 512;
    const int sWf1 = 16 * 12 * 512, sWf2 = 8  * 8  * 512;
    unsigned short *Wc1h = allocU(sWc1), *Wc1l = allocU(sWc1);
    unsigned short *Wc2h = allocU(sWc2), *Wc2l = allocU(sWc2);
    unsigned short *Wc3h = allocU(sWc3), *Wc3l = allocU(sWc3);
    unsigned short *Wg1h = allocU(sWg1), *Wg1l = allocU(sWg1);
    unsigned short *Wg2h = allocU(sWg2), *Wg2l = allocU(sWg2);
    unsigned short *Wr1h = allocU(sWr1), *Wr1l = allocU(sWr1);
    unsigned short *Wr2h = allocU(sWr2), *Wr2l = allocU(sWr2);
    unsigned short *Wr3h = allocU(sWr3), *Wr3l = allocU(sWr3);
    unsigned short *Wf1h = allocU(sWf1), *Wf1l = allocU(sWf1);
    unsigned short *Wf2h = allocU(sWf2), *Wf2l = allocU(sWf2);

    auto prep = [&](const float* W, int K, int N, int KS, int NT,
                    unsigned short* Bh, unsigned short* Bl) {
        const int total = NT * KS * 512;
        wprep<<<(total + 255) / 256, 256, 0, stream>>>(W, K, N, KS, NT, Bh, Bl);
    };
    prep(Wc1, 78, 78, 3, 8, Wc1h, Wc1l);
    prep(Wc2, 78, 156, 3, 12, Wc2h, Wc2l);
    prep(Wc3, 156, 312, 5, 20, Wc3h, Wc3l);
    prep(Wg1, 312, 156, 10, 12, Wg1h, Wg1l);
    prep(Wg2, 156, 128, 5, 8, Wg2h, Wg2l);
    prep(Wr1, 954, 512, 30, 32, Wr1h, Wr1l);
    prep(Wr2, 512, 256, 16, 16, Wr2h, Wr2l);
    prep(Wr3, 256, 128, 8, 8, Wr3h, Wr3l);
    prep(Wf1, 384, 256, 12, 16, Wf1h, Wf1l);
    prep(Wf2, 256, 128, 8, 8, Wf2h, Wf2l);

    l2norm_rows<<<BGRAPH, 256, 0, stream>>>(cell, CVN);

    // drug branches (GCN x3 + maxpool), MFMA-fused per graph
    gcn_graph<<<BGRAPH, GT, 0, stream>>>(x1, ei1, ei1 + EE,
        Wc1h, Wc1l, Wc2h, Wc2l, Wc3h, Wc3l, bc1, bc2, bc3, G1);
    gcn_graph<<<BGRAPH, GT, 0, stream>>>(x2, ei2, ei2 + EE,
        Wc1h, Wc1l, Wc2h, Wc2l, Wc3h, Wc3l, bc1, bc2, bc3, G2);

    // drug heads -> XC[:,0:128], XC[:,128:256]
    gemm_dense<3, true ><<<dim3(128, 1), 256, 0, stream>>>(G1, 312, 312, 10, Wg1h, Wg1l, bg1, 156, T, 156, 0);
    gemm_dense<1, false><<<dim3(128, 2), 256, 0, stream>>>(T, 156, 156, 5, Wg2h, Wg2l, bg2, 128, XC, 384, 0);
    gemm_dense<3, true ><<<dim3(128, 1), 256, 0, stream>>>(G2, 312, 312, 10, Wg1h, Wg1l, bg1, 156, T, 156, 0);
    gemm_dense<1, false><<<dim3(128, 2), 256, 0, stream>>>(T, 156, 156, 5, Wg2h, Wg2l, bg2, 128, XC, 384, 128);

    // cell MLP -> XC[:,256:384]
    gemm_dense<4, true ><<<dim3(128, 2), 256, 0, stream>>>(CVN, 954, 954, 30, Wr1h, Wr1l, br1, 512, C1, 512, 0);
    gemm_dense<2, true ><<<dim3(128, 2), 256, 0, stream>>>(C1, 512, 512, 16, Wr2h, Wr2l, br2, 256, C2, 256, 0);
    gemm_dense<1, false><<<dim3(128, 2), 256, 0, stream>>>(C2, 256, 256, 8, Wr3h, Wr3l, br3, 128, XC, 384, 256);

    // head
    gemm_dense<2, true ><<<dim3(128, 2), 256, 0, stream>>>(XC, 384, 384, 12, Wf1h, Wf1l, bf1, 256, H1, 256, 0);
    gemm_dense<1, true ><<<dim3(128, 2), 256, 0, stream>>>(H1, 256, 256, 8, Wf2h, Wf2l, bf2, 128, H2, 128, 0);
    wo_kernel<<<BGRAPH / 4, 256, 0, stream>>>(H2, Wo, bo, out);
}

// Round 5
// 1152.321 us; speedup vs baseline: 4.6188x; 1.1792x over previous
//
#include <hip/hip_runtime.h>
#include <math.h>

#define EE 819200          // edges total
#define BGRAPH 8192        // graphs
constexpr int GT = 512;    // threads, graph kernel (8 waves)

typedef __attribute__((ext_vector_type(8))) short bf16x8;   // 4 VGPRs = 8 bf16
typedef __attribute__((ext_vector_type(4))) float f32x4;

// ---- fp32 -> bf16 split (RNE), a ~= hi + lo, |a-(hi+lo)| <= 2^-18 |a| ----
__device__ inline unsigned short f2bf(float x) {
    unsigned u = __float_as_uint(x);
    u += 0x7fffu + ((u >> 16) & 1u);
    return (unsigned short)(u >> 16);
}
__device__ inline float bf2f(unsigned short h) {
    return __uint_as_float(((unsigned)h) << 16);
}
__device__ inline void split2(float v, unsigned short& hi, unsigned short& lo) {
    hi = f2bf(v);
    lo = f2bf(v - bf2f(hi));
}

// ---------------------------------------------------------------------------
// Fused weight prep (one launch): W[K][N] fp32 -> fragment-ordered hi/lo bf16,
// zero-padded to (KS*32) x (NT*16). Element order matches B-fragment loads:
//   idx = (((nt*KS + ks)*64 + lane)*8 + r) <-> k = ks*32+(lane>>4)*8+r,
//   n = nt*16 + (lane&15).
// ---------------------------------------------------------------------------
struct WDesc { const float* W; unsigned short* Bh; unsigned short* Bl;
               int K, N, KS, NT, base; };
struct WTab { WDesc d[10]; };

__global__ __launch_bounds__(256) void wprep_all(WTab tab)
{
    const int bid = blockIdx.x;
    int t = 0;
#pragma unroll
    for (int i = 1; i < 10; ++i) if (bid >= tab.d[i].base) t = i;
    const WDesc D = tab.d[t];
    const int idx = (bid - D.base) * 256 + (int)threadIdx.x;
    if (idx >= D.NT * D.KS * 512) return;
    const int r    = idx & 7;
    const int lane = (idx >> 3) & 63;
    const int rest = idx >> 9;
    const int ks   = rest % D.KS;
    const int nt   = rest / D.KS;
    const int k = ks * 32 + ((lane >> 4) << 3) + r;
    const int n = nt * 16 + (lane & 15);
    const float v = (k < D.K && n < D.N) ? D.W[(size_t)k * D.N + n] : 0.f;
    unsigned short h, l; split2(v, h, l);
    D.Bh[idx] = h; D.Bl[idx] = l;
}

// ---------------------------------------------------------------------------
// Per-graph fused 3-layer GCN + max pool, bf16x3 MFMA. Both drug branches in
// one launch (blockIdx.x >> 13 selects branch). 8 waves = 2 m-groups x 4
// n-groups. A (aggregated activations) split hi/lo bf16 in LDS [64][168];
// W fragments direct from global (L2-resident). act kept fp32 [50][160].
// ---------------------------------------------------------------------------

template<int KS, int NI>   // K-steps; n-tiles per wave (nt = ng + 4*i)
__device__ inline void layer_run(const unsigned short* __restrict__ Bh,
                                 const unsigned short* __restrict__ Bl,
                                 const unsigned short* Ah, const unsigned short* Al,
                                 f32x4 (&acc)[2][5], int mg, int ng, int lane)
{
#pragma unroll
    for (int m = 0; m < 2; ++m)
#pragma unroll
        for (int i = 0; i < NI; ++i) acc[m][i] = (f32x4){0.f, 0.f, 0.f, 0.f};
    const int g8 = (lane >> 4) << 3;
    for (int ks = 0; ks < KS; ++ks) {
        bf16x8 ah[2], al[2];
#pragma unroll
        for (int m = 0; m < 2; ++m) {
            const int off = (mg * 32 + m * 16 + (lane & 15)) * 168 + ks * 32 + g8;
            ah[m] = *(const bf16x8*)(Ah + off);
            al[m] = *(const bf16x8*)(Al + off);
        }
#pragma unroll
        for (int i = 0; i < NI; ++i) {
            const int nt = ng + (i << 2);
            const size_t bo = (size_t)((nt * KS + ks) * 64 + lane) * 8;
            const bf16x8 bh = *(const bf16x8*)(Bh + bo);
            const bf16x8 bl = *(const bf16x8*)(Bl + bo);
#pragma unroll
            for (int m = 0; m < 2; ++m) {
                acc[m][i] = __builtin_amdgcn_mfma_f32_16x16x32_bf16(ah[m], bh, acc[m][i], 0, 0, 0);
                acc[m][i] = __builtin_amdgcn_mfma_f32_16x16x32_bf16(al[m], bh, acc[m][i], 0, 0, 0);
                acc[m][i] = __builtin_amdgcn_mfma_f32_16x16x32_bf16(ah[m], bl, acc[m][i], 0, 0, 0);
            }
        }
    }
}

// D layout: col = lane&15 (+16*nt), row = (lane>>4)*4 + reg (+16*mt)
template<int NI, int NCOL>
__device__ inline void epi_store(const f32x4 (&acc)[2][5], const float* __restrict__ bias,
                                 float* act, int mg, int ng, int lane)
{
#pragma unroll
    for (int i = 0; i < NI; ++i) {
        const int col = (ng + (i << 2)) * 16 + (lane & 15);
        if (col < NCOL) {
            const float bj = bias[col];
#pragma unroll
            for (int m = 0; m < 2; ++m)
#pragma unroll
                for (int r = 0; r < 4; ++r) {
                    const int row = mg * 32 + m * 16 + ((lane >> 4) << 2) + r;
                    if (row < 50)
                        act[row * 160 + col] = fmaxf(acc[m][i][r] + bj, 0.f);
                }
        }
    }
}

__device__ inline void pool_store(const f32x4 (&acc)[2][5], const float* __restrict__ bias,
                                  unsigned* gmax, int mg, int ng, int lane)
{
#pragma unroll
    for (int i = 0; i < 5; ++i) {
        const int col = (ng + (i << 2)) * 16 + (lane & 15);
        const float bj = (col < 312) ? bias[col] : 0.f;
        float m = 0.f;                      // relu floor == pool identity
#pragma unroll
        for (int mm = 0; mm < 2; ++mm)
#pragma unroll
            for (int r = 0; r < 4; ++r) {
                const int row = mg * 32 + mm * 16 + ((lane >> 4) << 2) + r;
                if (row < 50) m = fmaxf(m, acc[mm][i][r] + bj);
            }
        m = fmaxf(m, __shfl_xor(m, 16, 64));
        m = fmaxf(m, __shfl_xor(m, 32, 64));
        if (lane < 16 && col < 312)
            atomicMax(&gmax[col], __float_as_uint(m));
    }
}

// agg (Â·H) fused with bf16-split, 4 features/item: float4 gathers with
// edge-pair unrolling (both addresses issued before use), ushort4 stores.
template<int NCOL>
__device__ inline void agg_split4(const float4* __restrict__ act4,
                                  unsigned short* Ah, unsigned short* Al,
                                  const int* insrc, const float* insn,
                                  const int* inoff, const float* selfw, int tid)
{
    constexpr int CH = (NCOL + 3) / 4;     // float4 chunks per row (pad cols zero)
    for (int idx = tid; idx < 50 * CH; idx += GT) {
        const int n = idx / CH;            // constexpr divisor -> magic-mul
        const int c = idx - n * CH;
        const float sw = selfw[n];
        float4 v = act4[n * 40 + c];
        float4 a; a.x = sw * v.x; a.y = sw * v.y; a.z = sw * v.z; a.w = sw * v.w;
        int j = inoff[n];
        const int j1 = inoff[n + 1];
        for (; j + 1 < j1; j += 2) {
            const int s0 = insrc[j], s1 = insrc[j + 1];
            const float w0 = insn[j], w1 = insn[j + 1];
            const float4 e0 = act4[s0 * 40 + c];
            const float4 e1 = act4[s1 * 40 + c];
            a.x = fmaf(w1, e1.x, fmaf(w0, e0.x, a.x));
            a.y = fmaf(w1, e1.y, fmaf(w0, e0.y, a.y));
            a.z = fmaf(w1, e1.z, fmaf(w0, e0.z, a.z));
            a.w = fmaf(w1, e1.w, fmaf(w0, e0.w, a.w));
        }
        if (j < j1) {
            const int s0 = insrc[j];
            const float w0 = insn[j];
            const float4 e0 = act4[s0 * 40 + c];
            a.x = fmaf(w0, e0.x, a.x);
            a.y = fmaf(w0, e0.y, a.y);
            a.z = fmaf(w0, e0.z, a.z);
            a.w = fmaf(w0, e0.w, a.w);
        }
        ushort4 h4, l4;
        split2(a.x, h4.x, l4.x);
        split2(a.y, h4.y, l4.y);
        split2(a.z, h4.z, l4.z);
        split2(a.w, h4.w, l4.w);
        *(ushort4*)(Ah + n * 168 + c * 4) = h4;   // 8B-aligned ds_write_b64
        *(ushort4*)(Al + n * 168 + c * 4) = l4;
    }
}

__global__ __launch_bounds__(GT) void gcn_graph(
    const float* __restrict__ x1, const int* __restrict__ ei1,
    const float* __restrict__ x2, const int* __restrict__ ei2,
    const unsigned short* __restrict__ W1h, const unsigned short* __restrict__ W1l,
    const unsigned short* __restrict__ W2h, const unsigned short* __restrict__ W2l,
    const unsigned short* __restrict__ W3h, const unsigned short* __restrict__ W3l,
    const float* __restrict__ bc1, const float* __restrict__ bc2, const float* __restrict__ bc3,
    float* __restrict__ G)              // [2*B,312]
{
    __shared__ unsigned short Ah[64 * 168], Al[64 * 168];   // split A frags
    __shared__ float4 act4[50 * 40];                        // fp32 activations [50][160]
    __shared__ int   es[100], ed[100], insrc[100];
    __shared__ float insn[100];
    __shared__ int   inoff[51], cnt[50];
    __shared__ float dinvs[50], selfw[50];
    __shared__ unsigned gmax[312];

    const int br = blockIdx.x >> 13;
    const int b  = blockIdx.x & (BGRAPH - 1);
    const float* X    = br ? x2 : x1;
    const int*   srcA = br ? ei2 : ei1;
    const int*   dstA = srcA + EE;
    const int nb = b * 50, eb = b * 100, tid = threadIdx.x;
    const int lane = tid & 63;
    const int w = tid >> 6;
    const int mg = w >> 2, ng = w & 3;
    float* act = (float*)act4;

    // ---- prologue: zero bufs (pads stay 0), CSR build, X load
    for (int i = tid; i < 64 * 168; i += GT) { Ah[i] = 0; Al[i] = 0; }
    for (int i = tid; i < 2000; i += GT) act4[i] = (float4){0.f, 0.f, 0.f, 0.f};
    for (int i = tid; i < 312; i += GT) gmax[i] = 0u;
    for (int i = tid; i < 50; i += GT) cnt[i] = 0;
    for (int e = tid; e < 100; e += GT) { es[e] = srcA[eb + e] - nb; ed[e] = dstA[eb + e] - nb; }
    __syncthreads();
    for (int e = tid; e < 100; e += GT) atomicAdd(&cnt[ed[e]], 1);
    __syncthreads();
    for (int n = tid; n < 50; n += GT) {
        const float dv = 1.0f / sqrtf((float)cnt[n] + 1.0f);
        dinvs[n] = dv; selfw[n] = dv * dv;
    }
    __syncthreads();
    if (tid == 0) { int off = 0; for (int n = 0; n < 50; ++n) { inoff[n] = off; off += cnt[n]; } inoff[50] = off; }
    __syncthreads();
    for (int n = tid; n < 50; n += GT) cnt[n] = 0;
    __syncthreads();
    for (int e = tid; e < 100; e += GT) {          // counting-sort edges by dst
        const int d = ed[e];
        const int p = inoff[d] + atomicAdd(&cnt[d], 1);
        insrc[p] = es[e];
        insn[p]  = dinvs[es[e]] * dinvs[d];
    }
    for (int idx = tid; idx < 50 * 78; idx += GT) {
        const int n = idx / 78, c = idx - n * 78;
        act[n * 160 + c] = X[(size_t)(nb + n) * 78 + c];
    }
    __syncthreads();

    f32x4 acc[2][5];

    // layer 1: agg(X) -> 78x78
    agg_split4<78>(act4, Ah, Al, insrc, insn, inoff, selfw, tid);
    __syncthreads();
    layer_run<3, 2>(W1h, W1l, Ah, Al, acc, mg, ng, lane);
    epi_store<2, 78>(acc, bc1, act, mg, ng, lane);
    __syncthreads();

    // layer 2: agg -> 78x156
    agg_split4<78>(act4, Ah, Al, insrc, insn, inoff, selfw, tid);
    __syncthreads();
    layer_run<3, 3>(W2h, W2l, Ah, Al, acc, mg, ng, lane);
    epi_store<3, 156>(acc, bc2, act, mg, ng, lane);
    __syncthreads();

    // layer 3: agg -> 156x312 + fused bias/relu/maxpool
    agg_split4<156>(act4, Ah, Al, insrc, insn, inoff, selfw, tid);
    __syncthreads();
    layer_run<5, 5>(W3h, W3l, Ah, Al, acc, mg, ng, lane);
    pool_store(acc, bc3, gmax, mg, ng, lane);
    __syncthreads();
    for (int f = tid; f < 312; f += GT)
        G[(size_t)(br * BGRAPH + b) * 312 + f] = __uint_as_float(gmax[f]);
}

// ---------------------------------------------------------------------------
// Dense bf16x3 MFMA GEMM: C = act(A[M,K] @ W[K,N] + b). BM=64, 4 waves, each
// wave owns 4 m-tiles x NTW n-tiles. A staged+split to LDS per 32-k step.
// ---------------------------------------------------------------------------
template<int NTW, bool RELU>
__global__ __launch_bounds__(256) void gemm_dense(
    const float* __restrict__ A, int lda, int K, int KS,
    const unsigned short* __restrict__ Bh, const unsigned short* __restrict__ Bl,
    const float* __restrict__ bias, int Nout,
    float* __restrict__ C, int ldc, int coff)
{
    __shared__ unsigned short Ahs[64 * 40], Als[64 * 40];
    const int tid = threadIdx.x, lane = tid & 63, w = tid >> 6;
    const int bm = blockIdx.x * 64;
    const int ntb = blockIdx.y * 4 * NTW;
    f32x4 acc[4][NTW];
#pragma unroll
    for (int m = 0; m < 4; ++m)
#pragma unroll
        for (int i = 0; i < NTW; ++i) acc[m][i] = (f32x4){0.f, 0.f, 0.f, 0.f};
    const int g8 = (lane >> 4) << 3;

    for (int ks = 0; ks < KS; ++ks) {
        __syncthreads();
        for (int idx = tid; idx < 2048; idx += 256) {
            const int row = idx >> 5, kk = idx & 31;
            const int k = ks * 32 + kk;
            const float v = (k < K) ? A[(size_t)(bm + row) * lda + k] : 0.f;
            unsigned short h, l; split2(v, h, l);
            Ahs[row * 40 + kk] = h; Als[row * 40 + kk] = l;
        }
        __syncthreads();
        bf16x8 ah[4], al[4];
#pragma unroll
        for (int m = 0; m < 4; ++m) {
            const int off = (m * 16 + (lane & 15)) * 40 + g8;
            ah[m] = *(const bf16x8*)(Ahs + off);
            al[m] = *(const bf16x8*)(Als + off);
        }
#pragma unroll
        for (int i = 0; i < NTW; ++i) {
            const int nt = ntb + w * NTW + i;
            const size_t bo = (size_t)((nt * KS + ks) * 64 + lane) * 8;
            const bf16x8 bh = *(const bf16x8*)(Bh + bo);
            const bf16x8 bl = *(const bf16x8*)(Bl + bo);
#pragma unroll
            for (int m = 0; m < 4; ++m) {
                acc[m][i] = __builtin_amdgcn_mfma_f32_16x16x32_bf16(ah[m], bh, acc[m][i], 0, 0, 0);
                acc[m][i] = __builtin_amdgcn_mfma_f32_16x16x32_bf16(al[m], bh, acc[m][i], 0, 0, 0);
                acc[m][i] = __builtin_amdgcn_mfma_f32_16x16x32_bf16(ah[m], bl, acc[m][i], 0, 0, 0);
            }
        }
    }
#pragma unroll
    for (int i = 0; i < NTW; ++i) {
        const int col = (ntb + w * NTW + i) * 16 + (lane & 15);
        if (col < Nout) {
            const float bj = bias[col];
#pragma unroll
            for (int m = 0; m < 4; ++m)
#pragma unroll
                for (int r = 0; r < 4; ++r) {
                    const int row = bm + m * 16 + ((lane >> 4) << 2) + r;
                    float v = acc[m][i][r] + bj;
                    if (RELU) v = fmaxf(v, 0.f);
                    C[(size_t)row * ldc + coff + col] = v;
                }
        }
    }
}

// ---------------------------------------------------------------------------
// Row-wise L2 normalize: Y[r,:] = X[r,:] / max(||X||, 1e-12), 954 cols
// ---------------------------------------------------------------------------
__global__ __launch_bounds__(256) void l2norm_rows(
    const float* __restrict__ X, float* __restrict__ Y)
{
    const int r = blockIdx.x;
    const float* row = X + (size_t)r * 954;
    float ss = 0.0f;
    for (int c = threadIdx.x; c < 954; c += 256) { const float v = row[c]; ss += v * v; }
    for (int off = 32; off > 0; off >>= 1) ss += __shfl_down(ss, off, 64);
    __shared__ float part[4];
    if ((threadIdx.x & 63) == 0) part[threadIdx.x >> 6] = ss;
    __syncthreads();
    if (threadIdx.x == 0) {
        const float s = part[0] + part[1] + part[2] + part[3];
        part[0] = 1.0f / fmaxf(sqrtf(s), 1e-12f);
    }
    __syncthreads();
    const float sc = part[0];
    for (int c = threadIdx.x; c < 954; c += 256)
        Y[(size_t)r * 954 + c] = row[c] * sc;
}

// final head: out[m,0:2] = Hh2[m,:] @ Wo + bo   (K=128, N=2) — one wave/row
__global__ __launch_bounds__(256) void wo_kernel(
    const float* __restrict__ H, const float* __restrict__ Wo,
    const float* __restrict__ bo, float* __restrict__ out)
{
    const int lane = threadIdx.x & 63;
    const int row = blockIdx.x * 4 + (threadIdx.x >> 6);
    const float a0 = H[(size_t)row * 128 + lane];
    const float a1 = H[(size_t)row * 128 + 64 + lane];
    float s0 = a0 * Wo[lane * 2]     + a1 * Wo[(64 + lane) * 2];
    float s1 = a0 * Wo[lane * 2 + 1] + a1 * Wo[(64 + lane) * 2 + 1];
    for (int off = 32; off > 0; off >>= 1) {
        s0 += __shfl_xor(s0, off, 64);
        s1 += __shfl_xor(s1, off, 64);
    }
    if (lane == 0) { out[row * 2] = s0 + bo[0]; out[row * 2 + 1] = s1 + bo[1]; }
}

// ---------------------------------------------------------------------------

extern "C" void kernel_launch(void* const* d_in, const int* in_sizes, int n_in,
                              void* d_out, int out_size, void* d_ws, size_t ws_size,
                              hipStream_t stream)
{
    (void)in_sizes; (void)n_in; (void)out_size; (void)ws_size;
    const float* x1   = (const float*)d_in[0];
    const int*   ei1  = (const int*)d_in[1];
    const float* x2   = (const float*)d_in[3];
    const int*   ei2  = (const int*)d_in[4];
    const float* cell = (const float*)d_in[6];
    const float* Wc1 = (const float*)d_in[7],  *bc1 = (const float*)d_in[8];
    const float* Wc2 = (const float*)d_in[9],  *bc2 = (const float*)d_in[10];
    const float* Wc3 = (const float*)d_in[11], *bc3 = (const float*)d_in[12];
    const float* Wg1 = (const float*)d_in[13], *bg1 = (const float*)d_in[14];
    const float* Wg2 = (const float*)d_in[15], *bg2 = (const float*)d_in[16];
    const float* Wr1 = (const float*)d_in[17], *br1 = (const float*)d_in[18];
    const float* Wr2 = (const float*)d_in[19], *br2 = (const float*)d_in[20];
    const float* Wr3 = (const float*)d_in[21], *br3 = (const float*)d_in[22];
    const float* Wf1 = (const float*)d_in[23], *bf1 = (const float*)d_in[24];
    const float* Wf2 = (const float*)d_in[25], *bf2 = (const float*)d_in[26];
    const float* Wo  = (const float*)d_in[27], *bo  = (const float*)d_in[28];
    float* out = (float*)d_out;
    float* ws  = (float*)d_ws;

    size_t o = 0;
    auto allocF = [&](size_t n) { float* p = ws + o; o += n; return p; };
    auto allocU = [&](size_t n) { unsigned short* p = (unsigned short*)(ws + o); o += n / 2; return p; };

    float* G1  = allocF((size_t)BGRAPH * 312);   // G2 contiguous after G1
    float* G2  = allocF((size_t)BGRAPH * 312);
    float* T   = allocF((size_t)BGRAPH * 156);
    float* CVN = allocF((size_t)BGRAPH * 954);
    float* C1  = allocF((size_t)BGRAPH * 512);
    float* C2  = allocF((size_t)BGRAPH * 256);
    float* XC  = allocF((size_t)BGRAPH * 384);
    float* H1  = allocF((size_t)BGRAPH * 256);
    float* H2  = allocF((size_t)BGRAPH * 128);

    // swizzled split weights (ushort counts = NT*KS*512)
    const int sWc1 = 8  * 3  * 512, sWc2 = 12 * 3  * 512, sWc3 = 20 * 5  * 512;
    const int sWg1 = 12 * 10 * 512, sWg2 = 8  * 5  * 512;
    const int sWr1 = 32 * 30 * 512, sWr2 = 16 * 16 * 512, sWr3 = 8 * 8 * 512;
    const int sWf1 = 16 * 12 * 512, sWf2 = 8  * 8  * 512;
    unsigned short *Wc1h = allocU(sWc1), *Wc1l = allocU(sWc1);
    unsigned short *Wc2h = allocU(sWc2), *Wc2l = allocU(sWc2);
    unsigned short *Wc3h = allocU(sWc3), *Wc3l = allocU(sWc3);
    unsigned short *Wg1h = allocU(sWg1), *Wg1l = allocU(sWg1);
    unsigned short *Wg2h = allocU(sWg2), *Wg2l = allocU(sWg2);
    unsigned short *Wr1h = allocU(sWr1), *Wr1l = allocU(sWr1);
    unsigned short *Wr2h = allocU(sWr2), *Wr2l = allocU(sWr2);
    unsigned short *Wr3h = allocU(sWr3), *Wr3l = allocU(sWr3);
    unsigned short *Wf1h = allocU(sWf1), *Wf1l = allocU(sWf1);
    unsigned short *Wf2h = allocU(sWf2), *Wf2l = allocU(sWf2);

    // one fused weight-prep launch
    WTab tab;
    int base = 0, ti = 0;
    auto addw = [&](const float* W, int K, int N, int KS, int NT,
                    unsigned short* Bh, unsigned short* Bl) {
        tab.d[ti] = WDesc{W, Bh, Bl, K, N, KS, NT, base};
        base += NT * KS * 2;              // blocks = NT*KS*512/256
        ++ti;
    };
    addw(Wc1, 78, 78, 3, 8, Wc1h, Wc1l);
    addw(Wc2, 78, 156, 3, 12, Wc2h, Wc2l);
    addw(Wc3, 156, 312, 5, 20, Wc3h, Wc3l);
    addw(Wg1, 312, 156, 10, 12, Wg1h, Wg1l);
    addw(Wg2, 156, 128, 5, 8, Wg2h, Wg2l);
    addw(Wr1, 954, 512, 30, 32, Wr1h, Wr1l);
    addw(Wr2, 512, 256, 16, 16, Wr2h, Wr2l);
    addw(Wr3, 256, 128, 8, 8, Wr3h, Wr3l);
    addw(Wf1, 384, 256, 12, 16, Wf1h, Wf1l);
    addw(Wf2, 256, 128, 8, 8, Wf2h, Wf2l);
    wprep_all<<<base, 256, 0, stream>>>(tab);

    l2norm_rows<<<BGRAPH, 256, 0, stream>>>(cell, CVN);

    // both drug branches (GCN x3 + maxpool) in one launch; G2 follows G1
    gcn_graph<<<2 * BGRAPH, GT, 0, stream>>>(x1, ei1, x2, ei2,
        Wc1h, Wc1l, Wc2h, Wc2l, Wc3h, Wc3l, bc1, bc2, bc3, G1);

    // drug heads -> XC[:,0:128], XC[:,128:256]
    gemm_dense<1, true ><<<dim3(128, 3), 256, 0, stream>>>(G1, 312, 312, 10, Wg1h, Wg1l, bg1, 156, T, 156, 0);
    gemm_dense<1, false><<<dim3(128, 2), 256, 0, stream>>>(T, 156, 156, 5, Wg2h, Wg2l, bg2, 128, XC, 384, 0);
    gemm_dense<1, true ><<<dim3(128, 3), 256, 0, stream>>>(G2, 312, 312, 10, Wg1h, Wg1l, bg1, 156, T, 156, 0);
    gemm_dense<1, false><<<dim3(128, 2), 256, 0, stream>>>(T, 156, 156, 5, Wg2h, Wg2l, bg2, 128, XC, 384, 128);

    // cell MLP -> XC[:,256:384]
    gemm_dense<4, true ><<<dim3(128, 2), 256, 0, stream>>>(CVN, 954, 954, 30, Wr1h, Wr1l, br1, 512, C1, 512, 0);
    gemm_dense<2, true ><<<dim3(128, 2), 256, 0, stream>>>(C1, 512, 512, 16, Wr2h, Wr2l, br2, 256, C2, 256, 0);
    gemm_dense<1, false><<<dim3(128, 2), 256, 0, stream>>>(C2, 256, 256, 8, Wr3h, Wr3l, br3, 128, XC, 384, 256);

    // head
    gemm_dense<2, true ><<<dim3(128, 2), 256, 0, stream>>>(XC, 384, 384, 12, Wf1h, Wf1l, bf1, 256, H1, 256, 0);
    gemm_dense<1, true ><<<dim3(128, 2), 256, 0, stream>>>(H1, 256, 256, 8, Wf2h, Wf2l, bf2, 128, H2, 128, 0);
    wo_kernel<<<BGRAPH / 4, 256, 0, stream>>>(H2, Wo, bo, out);
}